// Round 11
// baseline (1201.495 us; speedup 1.0000x reference)
//
#include <hip/hip_runtime.h>
#include <hip/hip_bf16.h>

// Problem constants (fixed by the reference setup)
#define H_DIM  128
#define NGRAPH 8192
#define NTOTAL 409600
#define NBLK2  (NTOTAL / 128)     // 3200 blocks of 8 waves x 16 nodes

#define NLOG2E -1.4426950408889634f

typedef __attribute__((ext_vector_type(8))) short    s16x8;   // 8 bf16
typedef __attribute__((ext_vector_type(4))) float    f32x4;   // MFMA accumulator
typedef __attribute__((ext_vector_type(4))) unsigned u32x4;

__device__ __forceinline__ unsigned short f2bf(float f) {
    unsigned int u = __float_as_uint(f);
    unsigned int r = u + 0x7fffu + ((u >> 16) & 1u);   // RNE
    return (unsigned short)(r >> 16);
}

// keep-alive helpers (rule #17): keep values live without cost, defeats DCE
__device__ __forceinline__ void keepv(const s16x8& v) {
    union { s16x8 s; u32x4 u; } c; c.s = v;
    asm volatile("" :: "v"(c.u[0]), "v"(c.u[1]), "v"(c.u[2]), "v"(c.u[3]));
}
__device__ __forceinline__ void keepv(const f32x4& v) {
    asm volatile("" :: "v"(v[0]), "v"(v[1]), "v"(v[2]), "v"(v[3]));
}

// ---------------- K0: w2bf = bf16(-log2e * W2), row-major [h][k] -------
__global__ void k0_w2(const float* __restrict__ W2w, unsigned short* __restrict__ w2bf) {
    int i = blockIdx.x * 256 + threadIdx.x;   // grid covers exactly 128*128
    w2bf[i] = f2bf(NLOG2E * W2w[i]);
}

// ---------------- K1: a_g = -log2e*(v_n @ W1^T + W1_b + W2_b); zero s_g
__global__ __launch_bounds__(128) void k1_ag(
    const float* __restrict__ node_emb,
    const int*   __restrict__ last_idx,
    const float* __restrict__ W1w,
    const float* __restrict__ W1b,
    const float* __restrict__ W2b,
    float* __restrict__ a_g,
    float* __restrict__ s_g)
{
    __shared__ float vn[4][H_DIM];
    const int tid = threadIdx.x;
    const int g0  = blockIdx.x * 4;
    #pragma unroll
    for (int g = 0; g < 4; g++) {
        int li = last_idx[g0 + g];
        vn[g][tid] = node_emb[(size_t)li * H_DIM + tid];
        s_g[(size_t)(g0 + g) * H_DIM + tid] = 0.f;   // zero-init for k2 atomics
    }
    __syncthreads();
    float b = W1b[tid] + W2b[tid];
    float a0 = b, a1 = b, a2 = b, a3 = b;
    const float* wrow = W1w + (size_t)tid * H_DIM;
    #pragma unroll 8
    for (int k = 0; k < H_DIM; k += 4) {
        float4 w = *reinterpret_cast<const float4*>(wrow + k);
        a0 += w.x * vn[0][k] + w.y * vn[0][k+1] + w.z * vn[0][k+2] + w.w * vn[0][k+3];
        a1 += w.x * vn[1][k] + w.y * vn[1][k+1] + w.z * vn[1][k+2] + w.w * vn[1][k+3];
        a2 += w.x * vn[2][k] + w.y * vn[2][k+1] + w.z * vn[2][k+2] + w.w * vn[2][k+3];
        a3 += w.x * vn[3][k] + w.y * vn[3][k+1] + w.z * vn[3][k+2] + w.w * vn[3][k+3];
    }
    a_g[(size_t)(g0 + 0) * H_DIM + tid] = NLOG2E * a0;
    a_g[(size_t)(g0 + 1) * H_DIM + tid] = NLOG2E * a1;
    a_g[(size_t)(g0 + 2) * H_DIM + tid] = NLOG2E * a2;
    a_g[(size_t)(g0 + 3) * H_DIM + tid] = NLOG2E * a3;
}

// ---------------- K2: one-shot fused alpha + segment-sum (R10, 107us) --
__global__ __launch_bounds__(512, 6) void k2_fused(
    const float* __restrict__ node_emb,
    const float* __restrict__ num_count,
    const int*   __restrict__ seg_ids,
    const float* __restrict__ a_g,
    const unsigned short* __restrict__ w2bf,
    const float* __restrict__ q_w,
    const float* __restrict__ q_b,
    float* __restrict__ s_g)
{
    __shared__ __align__(16) char w2s[H_DIM * 256];   // 32 KB, swizzled

    const int tid = threadIdx.x;
    {
        const uint4* wsrc = reinterpret_cast<const uint4*>(w2bf);
        #pragma unroll
        for (int i = 0; i < 4; i++) {
            int c = i * 512 + tid;
            uint4 v = wsrc[c];
            int byte = c << 4;
            int row  = byte >> 8;
            *reinterpret_cast<uint4*>(w2s + (byte ^ ((row & 7) << 4))) = v;
        }
    }

    const int bid = (int)blockIdx.x;
    const int swz = (bid & 7) * (NBLK2 / 8) + (bid >> 3);

    const int lane = tid & 63;
    const int wid  = tid >> 6;
    const int l16 = lane & 15, lq = lane >> 4;
    const int nb  = (swz * 8 + wid) * 16;

    const int   sgl = seg_ids[nb + l16];
    const float ncl = num_count[nb + l16];
    const float qb0 = q_b[0];

    const float* agrow = a_g + (size_t)sgl * H_DIM + lq * 4;
    f32x4 acc[8];
    #pragma unroll
    for (int nt = 0; nt < 8; nt++) {
        float4 a4 = *reinterpret_cast<const float4*>(agrow + nt * 16);
        acc[nt] = f32x4{a4.x, a4.y, a4.z, a4.w};
    }

    s16x8 af[4];
    const float* nrow = node_emb + (size_t)(nb + l16) * H_DIM + lq * 8;
    #pragma unroll
    for (int ks = 0; ks < 4; ks++) {
        float4 f0 = *reinterpret_cast<const float4*>(nrow + ks * 32);
        float4 f1 = *reinterpret_cast<const float4*>(nrow + ks * 32 + 4);
        unsigned p0, p1, p2, p3;
        asm("v_cvt_pk_bf16_f32 %0, %1, %2" : "=v"(p0) : "v"(f0.x), "v"(f0.y));
        asm("v_cvt_pk_bf16_f32 %0, %1, %2" : "=v"(p1) : "v"(f0.z), "v"(f0.w));
        asm("v_cvt_pk_bf16_f32 %0, %1, %2" : "=v"(p2) : "v"(f1.x), "v"(f1.y));
        asm("v_cvt_pk_bf16_f32 %0, %1, %2" : "=v"(p3) : "v"(f1.z), "v"(f1.w));
        union { u32x4 u; s16x8 s; } cv;
        cv.u = u32x4{p0, p1, p2, p3};
        af[ks] = cv.s;
    }

    __syncthreads();

    #pragma unroll
    for (int ks = 0; ks < 4; ks++) {
        #pragma unroll
        for (int nt = 0; nt < 8; nt++) {
            int row  = nt * 16 + l16;
            int byte = (row << 8) | ((lq * 8 + ks * 32) << 1);
            byte ^= (row & 7) << 4;
            s16x8 wfr = *reinterpret_cast<const s16x8*>(w2s + byte);
            acc[nt] = __builtin_amdgcn_mfma_f32_16x16x32_bf16(wfr, af[ks], acc[nt], 0, 0, 0);
        }
    }

    float pp0 = 0.f, pp1 = 0.f, pp2 = 0.f, pp3 = 0.f;
    #pragma unroll
    for (int nt = 0; nt < 8; nt++) {
        float4 q4 = *reinterpret_cast<const float4*>(q_w + nt * 16 + lq * 4);
        pp0 += q4.x * __builtin_amdgcn_rcpf(1.f + __builtin_amdgcn_exp2f(acc[nt][0]));
        pp1 += q4.y * __builtin_amdgcn_rcpf(1.f + __builtin_amdgcn_exp2f(acc[nt][1]));
        pp2 += q4.z * __builtin_amdgcn_rcpf(1.f + __builtin_amdgcn_exp2f(acc[nt][2]));
        pp3 += q4.w * __builtin_amdgcn_rcpf(1.f + __builtin_amdgcn_exp2f(acc[nt][3]));
    }
    float p = (pp0 + pp1) + (pp2 + pp3);
    p += __shfl_xor(p, 16, 64);
    p += __shfl_xor(p, 32, 64);
    const float coefl = ncl * (p + qb0);

    s16x8 ib[2];
    #pragma unroll
    for (int b = 0; b < 2; b++) {
        int kk = l16 + 16 * b;
        #pragma unroll
        for (int e = 0; e < 8; e++)
            ib[b][e] = (kk == lq * 8 + e) ? (short)0x3F80 : (short)0;
    }
    f32x4 accT[4][2];
    #pragma unroll
    for (int ks = 0; ks < 4; ks++)
        #pragma unroll
        for (int b = 0; b < 2; b++)
            accT[ks][b] = __builtin_amdgcn_mfma_f32_16x16x32_bf16(
                              af[ks], ib[b], f32x4{0.f, 0.f, 0.f, 0.f}, 0, 0, 0);

    int r0 = 0;
    while (r0 < 16) {
        const int cur = __shfl(sgl, r0, 64);
        unsigned long long diff = __ballot(sgl != cur) & 0xFFFFull;
        diff &= ~((1ull << r0) - 1ull);
        const int r1 = diff ? (int)__builtin_ctzll(diff) : 16;

        const float cmask = (sgl == cur) ? coefl : 0.f;
        float cm[4];
        #pragma unroll
        for (int rr = 0; rr < 4; rr++)
            cm[rr] = __shfl(cmask, lq * 4 + rr, 64);

        #pragma unroll
        for (int ks = 0; ks < 4; ks++) {
            #pragma unroll
            for (int b = 0; b < 2; b++) {
                float s = cm[0] * accT[ks][b][0] + cm[1] * accT[ks][b][1]
                        + cm[2] * accT[ks][b][2] + cm[3] * accT[ks][b][3];
                s += __shfl_xor(s, 16, 64);
                s += __shfl_xor(s, 32, 64);
                if (lq == 0)
                    atomicAdd(s_g + (size_t)cur * H_DIM + ks * 32 + b * 16 + l16, s);
            }
        }
        r0 = r1;
    }
}

// ---------------- DIAGNOSTIC PROBES (run after k3; outputs unused) -----
// Cumulative phases of k2, looped niter times. `zero`==0 at runtime but
// opaque to the compiler -> forces per-iteration reload/recompute.
// PHASE 1: node stream + cvt.   PHASE 2: + a_g C-init + LDS reads + MFMAs.
// PHASE 3: + alpha trans chain. PHASE 4: full clone incl segsum+atomics.
template<int PHASE>
__global__ __launch_bounds__(512, 6) void k2_probe(
    const float* __restrict__ node_emb,
    const float* __restrict__ num_count,
    const int*   __restrict__ seg_ids,
    const float* __restrict__ a_g,
    const unsigned short* __restrict__ w2bf,
    const float* __restrict__ q_w,
    const float* __restrict__ q_b,
    float* __restrict__ s_g,
    int niter, int zero)
{
    __shared__ __align__(16) char w2s[H_DIM * 256];
    const int tid = threadIdx.x;
    if (PHASE >= 2) {
        const uint4* wsrc = reinterpret_cast<const uint4*>(w2bf);
        #pragma unroll
        for (int i = 0; i < 4; i++) {
            int c = i * 512 + tid;
            uint4 v = wsrc[c];
            int byte = c << 4;
            int row  = byte >> 8;
            *reinterpret_cast<uint4*>(w2s + (byte ^ ((row & 7) << 4))) = v;
        }
    }
    const int bid = (int)blockIdx.x;
    const int swz = (bid & 7) * (NBLK2 / 8) + (bid >> 3);
    const int lane = tid & 63;
    const int wid  = tid >> 6;
    const int l16 = lane & 15, lq = lane >> 4;
    const int nb  = (swz * 8 + wid) * 16;
    const float qb0 = q_b[0];

    s16x8 ib[2];
    #pragma unroll
    for (int b = 0; b < 2; b++) {
        int kk = l16 + 16 * b;
        #pragma unroll
        for (int e = 0; e < 8; e++)
            ib[b][e] = (kk == lq * 8 + e) ? (short)0x3F80 : (short)0;
    }
    if (PHASE >= 2) __syncthreads();

    #pragma unroll 1
    for (int it = 0; it < niter; it++) {
        const int vo = zero * it;   // runtime 0, defeats cross-iteration CSE

        // --- node fragments (all phases) ---
        const float* nrow = node_emb + (size_t)(nb + l16) * H_DIM + lq * 8 + vo;
        s16x8 af[4];
        #pragma unroll
        for (int ks = 0; ks < 4; ks++) {
            float4 f0 = *reinterpret_cast<const float4*>(nrow + ks * 32);
            float4 f1 = *reinterpret_cast<const float4*>(nrow + ks * 32 + 4);
            unsigned p0, p1, p2, p3;
            asm("v_cvt_pk_bf16_f32 %0, %1, %2" : "=v"(p0) : "v"(f0.x), "v"(f0.y));
            asm("v_cvt_pk_bf16_f32 %0, %1, %2" : "=v"(p1) : "v"(f0.z), "v"(f0.w));
            asm("v_cvt_pk_bf16_f32 %0, %1, %2" : "=v"(p2) : "v"(f1.x), "v"(f1.y));
            asm("v_cvt_pk_bf16_f32 %0, %1, %2" : "=v"(p3) : "v"(f1.z), "v"(f1.w));
            union { u32x4 u; s16x8 s; } cv;
            cv.u = u32x4{p0, p1, p2, p3};
            af[ks] = cv.s;
        }
        if (PHASE == 1) {
            keepv(af[0]); keepv(af[1]); keepv(af[2]); keepv(af[3]);
            continue;
        }

        // --- a_g C-init + z-MFMA + transpose MFMA ---
        const int sgl = seg_ids[nb + l16 + vo];
        const float* agrow = a_g + (size_t)sgl * H_DIM + lq * 4 + vo;
        f32x4 acc[8];
        #pragma unroll
        for (int nt = 0; nt < 8; nt++) {
            float4 a4 = *reinterpret_cast<const float4*>(agrow + nt * 16);
            acc[nt] = f32x4{a4.x, a4.y, a4.z, a4.w};
        }
        #pragma unroll
        for (int ks = 0; ks < 4; ks++) {
            #pragma unroll
            for (int nt = 0; nt < 8; nt++) {
                int row  = nt * 16 + l16;
                int byte = (row << 8) | ((lq * 8 + ks * 32) << 1);
                byte = (byte ^ ((row & 7) << 4)) + vo;
                s16x8 wfr = *reinterpret_cast<const s16x8*>(w2s + byte);
                acc[nt] = __builtin_amdgcn_mfma_f32_16x16x32_bf16(wfr, af[ks], acc[nt], 0, 0, 0);
            }
        }
        f32x4 accT[4][2];
        #pragma unroll
        for (int ks = 0; ks < 4; ks++)
            #pragma unroll
            for (int b = 0; b < 2; b++)
                accT[ks][b] = __builtin_amdgcn_mfma_f32_16x16x32_bf16(
                                  af[ks], ib[b], f32x4{0.f, 0.f, 0.f, 0.f}, 0, 0, 0);
        if (PHASE == 2) {
            #pragma unroll
            for (int nt = 0; nt < 8; nt++) keepv(acc[nt]);
            #pragma unroll
            for (int ks = 0; ks < 4; ks++) { keepv(accT[ks][0]); keepv(accT[ks][1]); }
            continue;
        }

        // --- alpha trans chain ---
        const float ncl = num_count[nb + l16 + vo];
        float pp0 = 0.f, pp1 = 0.f, pp2 = 0.f, pp3 = 0.f;
        #pragma unroll
        for (int nt = 0; nt < 8; nt++) {
            float4 q4 = *reinterpret_cast<const float4*>(q_w + nt * 16 + lq * 4 + vo);
            pp0 += q4.x * __builtin_amdgcn_rcpf(1.f + __builtin_amdgcn_exp2f(acc[nt][0]));
            pp1 += q4.y * __builtin_amdgcn_rcpf(1.f + __builtin_amdgcn_exp2f(acc[nt][1]));
            pp2 += q4.z * __builtin_amdgcn_rcpf(1.f + __builtin_amdgcn_exp2f(acc[nt][2]));
            pp3 += q4.w * __builtin_amdgcn_rcpf(1.f + __builtin_amdgcn_exp2f(acc[nt][3]));
        }
        float p = (pp0 + pp1) + (pp2 + pp3);
        p += __shfl_xor(p, 16, 64);
        p += __shfl_xor(p, 32, 64);
        const float coefl = ncl * (p + qb0);
        if (PHASE == 3) {
            asm volatile("" :: "v"(coefl));
            #pragma unroll
            for (int ks = 0; ks < 4; ks++) { keepv(accT[ks][0]); keepv(accT[ks][1]); }
            continue;
        }

        // --- PHASE 4: full segsum + atomics (s_g is dead post-k3) ---
        int r0 = 0;
        while (r0 < 16) {
            const int cur = __shfl(sgl, r0, 64);
            unsigned long long diff = __ballot(sgl != cur) & 0xFFFFull;
            diff &= ~((1ull << r0) - 1ull);
            const int r1 = diff ? (int)__builtin_ctzll(diff) : 16;
            const float cmask = (sgl == cur) ? coefl : 0.f;
            float cm[4];
            #pragma unroll
            for (int rr = 0; rr < 4; rr++)
                cm[rr] = __shfl(cmask, lq * 4 + rr, 64);
            #pragma unroll
            for (int ks = 0; ks < 4; ks++) {
                #pragma unroll
                for (int b = 0; b < 2; b++) {
                    float s = cm[0] * accT[ks][b][0] + cm[1] * accT[ks][b][1]
                            + cm[2] * accT[ks][b][2] + cm[3] * accT[ks][b][3];
                    s += __shfl_xor(s, 16, 64);
                    s += __shfl_xor(s, 32, 64);
                    if (lq == 0)
                        atomicAdd(s_g + (size_t)cur * H_DIM + ks * 32 + b * 16 + l16, s);
                }
            }
            r0 = r1;
        }
    }
}

// ---------------- K3: s_h = [v_n | s_g] @ W3^T + W3_b ------------------
__global__ __launch_bounds__(128) void k3_out(
    const float* __restrict__ node_emb,
    const int*   __restrict__ last_idx,
    const float* __restrict__ s_g,
    const float* __restrict__ W3w,
    const float* __restrict__ W3b,
    float* __restrict__ out)
{
    __shared__ float cat[8][2 * H_DIM];
    const int tid = threadIdx.x;
    const int g0  = blockIdx.x * 8;
    #pragma unroll
    for (int g = 0; g < 8; g++) {
        cat[g][tid]         = node_emb[(size_t)last_idx[g0 + g] * H_DIM + tid];
        cat[g][H_DIM + tid] = s_g[(size_t)(g0 + g) * H_DIM + tid];
    }
    __syncthreads();
    float acc[8];
    float b = W3b[tid];
    #pragma unroll
    for (int g = 0; g < 8; g++) acc[g] = b;
    const float* wrow = W3w + (size_t)tid * (2 * H_DIM);
    for (int k = 0; k < 2 * H_DIM; k += 4) {
        float4 w = *reinterpret_cast<const float4*>(wrow + k);
        #pragma unroll
        for (int g = 0; g < 8; g++)
            acc[g] += w.x * cat[g][k] + w.y * cat[g][k+1]
                    + w.z * cat[g][k+2] + w.w * cat[g][k+3];
    }
    #pragma unroll
    for (int g = 0; g < 8; g++)
        out[(size_t)(g0 + g) * H_DIM + tid] = acc[g];
}

extern "C" void kernel_launch(void* const* d_in, const int* in_sizes, int n_in,
                              void* d_out, int out_size, void* d_ws, size_t ws_size,
                              hipStream_t stream) {
    const float* node_emb  = (const float*)d_in[0];
    const float* num_count = (const float*)d_in[1];
    const int*   seg_ids   = (const int*)d_in[3];
    const int*   last_idx  = (const int*)d_in[4];
    const float* W1w = (const float*)d_in[9];
    const float* W1b = (const float*)d_in[10];
    const float* W2w = (const float*)d_in[11];
    const float* W2b = (const float*)d_in[12];
    const float* qw  = (const float*)d_in[13];
    const float* qb  = (const float*)d_in[14];
    const float* W3w = (const float*)d_in[15];
    const float* W3b = (const float*)d_in[16];
    float* out = (float*)d_out;

    char* ws = (char*)d_ws;
    float* a_g = (float*)(ws);                          // 4 MB
    float* s_g = (float*)(ws + (4u << 20));             // 4 MB
    unsigned short* w2bf = (unsigned short*)(ws + (8u << 20));   // 32 KB

    k0_w2   <<<64,         256, 0, stream>>>(W2w, w2bf);
    k1_ag   <<<NGRAPH / 4, 128, 0, stream>>>(node_emb, last_idx, W1w, W1b, W2b, a_g, s_g);
    k2_fused<<<NBLK2,      512, 0, stream>>>(node_emb, num_count, seg_ids, a_g,
                                             w2bf, qw, qb, s_g);
    k3_out  <<<NGRAPH / 8, 128, 0, stream>>>(node_emb, last_idx, s_g, W3w, W3b, out);

    // ---- diagnostic probes (do not touch d_out; s_g dead after k3) ----
    k2_probe<1><<<NBLK2, 512, 0, stream>>>(node_emb, num_count, seg_ids, a_g,
                                           w2bf, qw, qb, s_g, 8, 0);
    k2_probe<2><<<NBLK2, 512, 0, stream>>>(node_emb, num_count, seg_ids, a_g,
                                           w2bf, qw, qb, s_g, 5, 0);
    k2_probe<3><<<NBLK2, 512, 0, stream>>>(node_emb, num_count, seg_ids, a_g,
                                           w2bf, qw, qb, s_g, 4, 0);
    k2_probe<4><<<NBLK2, 512, 0, stream>>>(node_emb, num_count, seg_ids, a_g,
                                           w2bf, qw, qb, s_g, 3, 0);
}

// Round 12
// 185.117 us; speedup vs baseline: 6.4905x; 6.4905x over previous
//
#include <hip/hip_runtime.h>
#include <hip/hip_bf16.h>

// Problem constants (fixed by the reference setup)
#define H_DIM  128
#define NGRAPH 8192
#define NTOTAL 409600
#define NBLK2  (NTOTAL / 128)     // 3200 blocks of 8 waves x 16 nodes
#define MAXLOC 14                 // max graphs overlapping 128 rows (min size 10)

#define NLOG2E -1.4426950408889634f

typedef __attribute__((ext_vector_type(8))) short    s16x8;   // 8 bf16
typedef __attribute__((ext_vector_type(4))) float    f32x4;   // MFMA accumulator
typedef __attribute__((ext_vector_type(4))) unsigned u32x4;

__device__ __forceinline__ unsigned short f2bf(float f) {
    unsigned int u = __float_as_uint(f);
    unsigned int r = u + 0x7fffu + ((u >> 16) & 1u);   // RNE
    return (unsigned short)(r >> 16);
}

// ---------------- K0: w2bf = bf16(-log2e * W2), row-major [h][k] -------
__global__ void k0_w2(const float* __restrict__ W2w, unsigned short* __restrict__ w2bf) {
    int i = blockIdx.x * 256 + threadIdx.x;   // grid covers exactly 128*128
    w2bf[i] = f2bf(NLOG2E * W2w[i]);
}

// ---------------- K1: a_g = -log2e*(v_n @ W1^T + W1_b + W2_b) ----------
__global__ __launch_bounds__(128) void k1_ag(
    const float* __restrict__ node_emb,
    const int*   __restrict__ last_idx,
    const float* __restrict__ W1w,
    const float* __restrict__ W1b,
    const float* __restrict__ W2b,
    float* __restrict__ a_g)
{
    __shared__ float vn[4][H_DIM];
    const int tid = threadIdx.x;
    const int g0  = blockIdx.x * 4;
    #pragma unroll
    for (int g = 0; g < 4; g++) {
        int li = last_idx[g0 + g];
        vn[g][tid] = node_emb[(size_t)li * H_DIM + tid];
    }
    __syncthreads();
    float b = W1b[tid] + W2b[tid];
    float a0 = b, a1 = b, a2 = b, a3 = b;
    const float* wrow = W1w + (size_t)tid * H_DIM;
    #pragma unroll 8
    for (int k = 0; k < H_DIM; k += 4) {
        float4 w = *reinterpret_cast<const float4*>(wrow + k);
        a0 += w.x * vn[0][k] + w.y * vn[0][k+1] + w.z * vn[0][k+2] + w.w * vn[0][k+3];
        a1 += w.x * vn[1][k] + w.y * vn[1][k+1] + w.z * vn[1][k+2] + w.w * vn[1][k+3];
        a2 += w.x * vn[2][k] + w.y * vn[2][k+1] + w.z * vn[2][k+2] + w.w * vn[2][k+3];
        a3 += w.x * vn[3][k] + w.y * vn[3][k+1] + w.z * vn[3][k+2] + w.w * vn[3][k+3];
    }
    a_g[(size_t)(g0 + 0) * H_DIM + tid] = NLOG2E * a0;
    a_g[(size_t)(g0 + 1) * H_DIM + tid] = NLOG2E * a1;
    a_g[(size_t)(g0 + 2) * H_DIM + tid] = NLOG2E * a2;
    a_g[(size_t)(g0 + 3) * H_DIM + tid] = NLOG2E * a3;
}

// ---------------- K2: fused alpha + segment-sum, NO global atomics -----
// 3200 blocks x 512 threads (8 waves x 16 nodes = 128 rows/block).
// Per-run partials go to a block-local LDS table (ds_add_f32). Epilogue:
// interior graphs -> plain store to s_g; the <=2 boundary graphs -> part[].
__global__ __launch_bounds__(512, 8) void k2_fused(
    const float* __restrict__ node_emb,
    const float* __restrict__ num_count,
    const int*   __restrict__ seg_ids,
    const int*   __restrict__ last_idx,
    const float* __restrict__ a_g,
    const unsigned short* __restrict__ w2bf,
    const float* __restrict__ q_w,
    const float* __restrict__ q_b,
    float* __restrict__ s_g,
    float* __restrict__ part)
{
    __shared__ __align__(16) char w2s[H_DIM * 256];    // 32 KB, swizzled
    __shared__ float ldsS[MAXLOC][H_DIM];              // 7 KB partial table

    const int tid = threadIdx.x;
    // --- zero partial table + stage W2 bf16 -> LDS, XOR swizzled ---
    {
        float* z = &ldsS[0][0];
        #pragma unroll
        for (int i = tid; i < MAXLOC * H_DIM; i += 512) z[i] = 0.f;
        const uint4* wsrc = reinterpret_cast<const uint4*>(w2bf);
        #pragma unroll
        for (int i = 0; i < 4; i++) {
            int c = i * 512 + tid;
            uint4 v = wsrc[c];
            int byte = c << 4;
            int row  = byte >> 8;
            *reinterpret_cast<uint4*>(w2s + (byte ^ ((row & 7) << 4))) = v;
        }
    }

    // XCD-aware bijective swizzle (3200 % 8 == 0)
    const int bid = (int)blockIdx.x;
    const int swz = (bid & 7) * (NBLK2 / 8) + (bid >> 3);   // logical block id

    const int lane = tid & 63;
    const int wid  = tid >> 6;                 // 0..7
    const int l16 = lane & 15, lq = lane >> 4;
    const int nbB = swz * 128;                 // block's first node row
    const int nb  = nbB + wid * 16;            // this wave's 16 nodes

    const int   sg0 = seg_ids[nbB];            // block's first graph
    const int   sgl = seg_ids[nb + l16];
    const float ncl = num_count[nb + l16];
    const float qb0 = q_b[0];

    // --- a_g row (prescaled) as MFMA C-init ---
    const float* agrow = a_g + (size_t)sgl * H_DIM + lq * 4;
    f32x4 acc[8];
    #pragma unroll
    for (int nt = 0; nt < 8; nt++) {
        float4 a4 = *reinterpret_cast<const float4*>(agrow + nt * 16);
        acc[nt] = f32x4{a4.x, a4.y, a4.z, a4.w};
    }

    // --- node fragments: row l16, cols lq*8 + ks*32 .. +7 (f32 -> bf16) ---
    s16x8 af[4];
    const float* nrow = node_emb + (size_t)(nb + l16) * H_DIM + lq * 8;
    #pragma unroll
    for (int ks = 0; ks < 4; ks++) {
        float4 f0 = *reinterpret_cast<const float4*>(nrow + ks * 32);
        float4 f1 = *reinterpret_cast<const float4*>(nrow + ks * 32 + 4);
        unsigned p0, p1, p2, p3;
        asm("v_cvt_pk_bf16_f32 %0, %1, %2" : "=v"(p0) : "v"(f0.x), "v"(f0.y));
        asm("v_cvt_pk_bf16_f32 %0, %1, %2" : "=v"(p1) : "v"(f0.z), "v"(f0.w));
        asm("v_cvt_pk_bf16_f32 %0, %1, %2" : "=v"(p2) : "v"(f1.x), "v"(f1.y));
        asm("v_cvt_pk_bf16_f32 %0, %1, %2" : "=v"(p3) : "v"(f1.z), "v"(f1.w));
        union { u32x4 u; s16x8 s; } cv;
        cv.u = u32x4{p0, p1, p2, p3};
        af[ks] = cv.s;
    }

    __syncthreads();   // w2s + zeroed ldsS visible

    // --- swapped z-MFMA: lane holds z'[l16][h] = -log2e*(z+a_g) ----------
    #pragma unroll
    for (int ks = 0; ks < 4; ks++) {
        #pragma unroll
        for (int nt = 0; nt < 8; nt++) {
            int row  = nt * 16 + l16;
            int byte = (row << 8) | ((lq * 8 + ks * 32) << 1);
            byte ^= (row & 7) << 4;
            s16x8 wfr = *reinterpret_cast<const s16x8*>(w2s + byte);
            acc[nt] = __builtin_amdgcn_mfma_f32_16x16x32_bf16(wfr, af[ks], acc[nt], 0, 0, 0);
        }
    }

    // --- alpha: sum_h q_w[h] / (1 + exp2(z')); 2-shfl reduce -------------
    float pp0 = 0.f, pp1 = 0.f, pp2 = 0.f, pp3 = 0.f;
    #pragma unroll
    for (int nt = 0; nt < 8; nt++) {
        float4 q4 = *reinterpret_cast<const float4*>(q_w + nt * 16 + lq * 4);
        pp0 += q4.x * __builtin_amdgcn_rcpf(1.f + __builtin_amdgcn_exp2f(acc[nt][0]));
        pp1 += q4.y * __builtin_amdgcn_rcpf(1.f + __builtin_amdgcn_exp2f(acc[nt][1]));
        pp2 += q4.z * __builtin_amdgcn_rcpf(1.f + __builtin_amdgcn_exp2f(acc[nt][2]));
        pp3 += q4.w * __builtin_amdgcn_rcpf(1.f + __builtin_amdgcn_exp2f(acc[nt][3]));
    }
    float p = (pp0 + pp1) + (pp2 + pp3);
    p += __shfl_xor(p, 16, 64);
    p += __shfl_xor(p, 32, 64);
    const float coefl = ncl * (p + qb0);   // coef for node row l16, all lanes

    // --- identity-MFMA transpose: accT[ks][b][rr] = node[lq*4+rr][...] ---
    s16x8 ib[2];
    #pragma unroll
    for (int b = 0; b < 2; b++) {
        int kk = l16 + 16 * b;
        #pragma unroll
        for (int e = 0; e < 8; e++)
            ib[b][e] = (kk == lq * 8 + e) ? (short)0x3F80 : (short)0;
    }
    f32x4 accT[4][2];
    #pragma unroll
    for (int ks = 0; ks < 4; ks++)
        #pragma unroll
        for (int b = 0; b < 2; b++)
            accT[ks][b] = __builtin_amdgcn_mfma_f32_16x16x32_bf16(
                              af[ks], ib[b], f32x4{0.f, 0.f, 0.f, 0.f}, 0, 0, 0);

    // --- segmented sum: per-run ds_add into block-local table ------------
    int r0 = 0;
    while (r0 < 16) {
        const int cur = __shfl(sgl, r0, 64);                 // wave-uniform
        unsigned long long diff = __ballot(sgl != cur) & 0xFFFFull;
        diff &= ~((1ull << r0) - 1ull);
        const int r1 = diff ? (int)__builtin_ctzll(diff) : 16;

        const float cmask = (sgl == cur) ? coefl : 0.f;      // masked coef of row l16
        float cm[4];
        #pragma unroll
        for (int rr = 0; rr < 4; rr++)
            cm[rr] = __shfl(cmask, lq * 4 + rr, 64);

        const int loc = cur - sg0;                           // 0..13
        #pragma unroll
        for (int ks = 0; ks < 4; ks++) {
            #pragma unroll
            for (int b = 0; b < 2; b++) {
                float s = cm[0] * accT[ks][b][0] + cm[1] * accT[ks][b][1]
                        + cm[2] * accT[ks][b][2] + cm[3] * accT[ks][b][3];
                atomicAdd(&ldsS[loc][ks * 32 + b * 16 + l16], s);  // ds_add_f32
            }
        }
        r0 = r1;
    }
    __syncthreads();   // partial table complete

    // --- epilogue: interior graphs -> s_g; boundary graphs -> part ------
    {
        const int sgL  = seg_ids[nbB + 127];
        const int nloc = sgL - sg0 + 1;
        const int col  = tid & 127;
        for (int j = tid >> 7; j < nloc; j += 4) {
            const int gg = sg0 + j;
            const int st = gg ? (last_idx[gg - 1] + 1) : 0;
            const int en = last_idx[gg];
            const float v = ldsS[j][col];
            const bool interior = (st >= nbB) && (en < nbB + 128);
            if (interior) {
                s_g[(size_t)gg * H_DIM + col] = v;
            } else if (j == 0) {
                part[((size_t)swz * 2 + 0) * H_DIM + col] = v;   // slot 0
            } else {
                part[((size_t)swz * 2 + 1) * H_DIM + col] = v;   // slot 1 (j==nloc-1)
            }
        }
    }
}

// ---------------- K2b: gather boundary-graph partials ------------------
__global__ __launch_bounds__(128) void k2b_gather(
    const int*   __restrict__ last_idx,
    const float* __restrict__ part,
    float* __restrict__ s_g)
{
    const int g   = blockIdx.x;
    const int col = threadIdx.x;
    const int st  = g ? (last_idx[g - 1] + 1) : 0;
    const int en  = last_idx[g];
    const int bs  = st >> 7, be = en >> 7;
    if (bs == be) return;                       // interior: k2 stored it
    const int slot0 = (st == (bs << 7)) ? 0 : 1;
    float s = part[((size_t)bs * 2 + slot0) * H_DIM + col];
    for (int m = bs + 1; m <= be; m++)
        s += part[((size_t)m * 2 + 0) * H_DIM + col];
    s_g[(size_t)g * H_DIM + col] = s;
}

// ---------------- K3: s_h = [v_n | s_g] @ W3^T + W3_b ------------------
__global__ __launch_bounds__(128) void k3_out(
    const float* __restrict__ node_emb,
    const int*   __restrict__ last_idx,
    const float* __restrict__ s_g,
    const float* __restrict__ W3w,
    const float* __restrict__ W3b,
    float* __restrict__ out)
{
    __shared__ float cat[8][2 * H_DIM];
    const int tid = threadIdx.x;
    const int g0  = blockIdx.x * 8;
    #pragma unroll
    for (int g = 0; g < 8; g++) {
        cat[g][tid]         = node_emb[(size_t)last_idx[g0 + g] * H_DIM + tid];
        cat[g][H_DIM + tid] = s_g[(size_t)(g0 + g) * H_DIM + tid];
    }
    __syncthreads();
    float acc[8];
    float b = W3b[tid];
    #pragma unroll
    for (int g = 0; g < 8; g++) acc[g] = b;
    const float* wrow = W3w + (size_t)tid * (2 * H_DIM);
    for (int k = 0; k < 2 * H_DIM; k += 4) {
        float4 w = *reinterpret_cast<const float4*>(wrow + k);
        #pragma unroll
        for (int g = 0; g < 8; g++)
            acc[g] += w.x * cat[g][k] + w.y * cat[g][k+1]
                    + w.z * cat[g][k+2] + w.w * cat[g][k+3];
    }
    #pragma unroll
    for (int g = 0; g < 8; g++)
        out[(size_t)(g0 + g) * H_DIM + tid] = acc[g];
}

extern "C" void kernel_launch(void* const* d_in, const int* in_sizes, int n_in,
                              void* d_out, int out_size, void* d_ws, size_t ws_size,
                              hipStream_t stream) {
    const float* node_emb  = (const float*)d_in[0];
    const float* num_count = (const float*)d_in[1];
    // d_in[2] sections: unused
    const int*   seg_ids   = (const int*)d_in[3];
    const int*   last_idx  = (const int*)d_in[4];
    // d_in[5..8] unused
    const float* W1w = (const float*)d_in[9];
    const float* W1b = (const float*)d_in[10];
    const float* W2w = (const float*)d_in[11];
    const float* W2b = (const float*)d_in[12];
    const float* qw  = (const float*)d_in[13];
    const float* qb  = (const float*)d_in[14];
    const float* W3w = (const float*)d_in[15];
    const float* W3b = (const float*)d_in[16];
    float* out = (float*)d_out;

    char* ws = (char*)d_ws;
    float* a_g  = (float*)(ws);                          // 4 MB
    float* s_g  = (float*)(ws + (4u << 20));             // 4 MB
    unsigned short* w2bf = (unsigned short*)(ws + (8u << 20));   // 32 KB
    float* part = (float*)(ws + (9u << 20));             // 3200*2*128*4 = 3.3 MB

    k0_w2     <<<64,         256, 0, stream>>>(W2w, w2bf);
    k1_ag     <<<NGRAPH / 4, 128, 0, stream>>>(node_emb, last_idx, W1w, W1b, W2b, a_g);
    k2_fused  <<<NBLK2,      512, 0, stream>>>(node_emb, num_count, seg_ids, last_idx,
                                               a_g, w2bf, qw, qb, s_g, part);
    k2b_gather<<<NGRAPH,     128, 0, stream>>>(last_idx, part, s_g);
    k3_out    <<<NGRAPH / 8, 128, 0, stream>>>(node_emb, last_idx, s_g, W3w, W3b, out);
}

// Round 13
// 113.115 us; speedup vs baseline: 10.6219x; 1.6365x over previous
//
#include <hip/hip_runtime.h>
#include <hip/hip_bf16.h>

// Problem constants (fixed by the reference setup)
#define H_DIM  128
#define NGRAPH 8192
#define NTOTAL 409600
#define NBLK2  (NTOTAL / 128)     // 3200 blocks of 8 waves x 16 nodes
#define MAXLOC 14                 // max graphs overlapping 128 rows (min size 10)

#define NLOG2E -1.4426950408889634f

typedef __attribute__((ext_vector_type(8))) short    s16x8;   // 8 bf16
typedef __attribute__((ext_vector_type(4))) float    f32x4;   // MFMA accumulator
typedef __attribute__((ext_vector_type(4))) unsigned u32x4;

__device__ __forceinline__ unsigned short f2bf(float f) {
    unsigned int u = __float_as_uint(f);
    unsigned int r = u + 0x7fffu + ((u >> 16) & 1u);   // RNE
    return (unsigned short)(r >> 16);
}

// ---------------- K0: w2bf = bf16(-log2e * W2), row-major [h][k] -------
__global__ void k0_w2(const float* __restrict__ W2w, unsigned short* __restrict__ w2bf) {
    int i = blockIdx.x * 256 + threadIdx.x;   // grid covers exactly 128*128
    w2bf[i] = f2bf(NLOG2E * W2w[i]);
}

// ---------------- K1: a_g = -log2e*(v_n @ W1^T + W1_b + W2_b) ----------
__global__ __launch_bounds__(128) void k1_ag(
    const float* __restrict__ node_emb,
    const int*   __restrict__ last_idx,
    const float* __restrict__ W1w,
    const float* __restrict__ W1b,
    const float* __restrict__ W2b,
    float* __restrict__ a_g)
{
    __shared__ float vn[4][H_DIM];
    const int tid = threadIdx.x;
    const int g0  = blockIdx.x * 4;
    #pragma unroll
    for (int g = 0; g < 4; g++) {
        int li = last_idx[g0 + g];
        vn[g][tid] = node_emb[(size_t)li * H_DIM + tid];
    }
    __syncthreads();
    float b = W1b[tid] + W2b[tid];
    float a0 = b, a1 = b, a2 = b, a3 = b;
    const float* wrow = W1w + (size_t)tid * H_DIM;
    #pragma unroll 8
    for (int k = 0; k < H_DIM; k += 4) {
        float4 w = *reinterpret_cast<const float4*>(wrow + k);
        a0 += w.x * vn[0][k] + w.y * vn[0][k+1] + w.z * vn[0][k+2] + w.w * vn[0][k+3];
        a1 += w.x * vn[1][k] + w.y * vn[1][k+1] + w.z * vn[1][k+2] + w.w * vn[1][k+3];
        a2 += w.x * vn[2][k] + w.y * vn[2][k+1] + w.z * vn[2][k+2] + w.w * vn[2][k+3];
        a3 += w.x * vn[3][k] + w.y * vn[3][k+1] + w.z * vn[3][k+2] + w.w * vn[3][k+3];
    }
    a_g[(size_t)(g0 + 0) * H_DIM + tid] = NLOG2E * a0;
    a_g[(size_t)(g0 + 1) * H_DIM + tid] = NLOG2E * a1;
    a_g[(size_t)(g0 + 2) * H_DIM + tid] = NLOG2E * a2;
    a_g[(size_t)(g0 + 3) * H_DIM + tid] = NLOG2E * a3;
}

// ---------------- K2: fused alpha + segment-sum (LDS table, no global
// atomics). 3200 blocks x 512 threads (8 waves x 16 nodes). R10 register
// budget (512,6); segsum = shfl-fold -> conflict-free ds_add -> epilogue.
__global__ __launch_bounds__(512, 6) void k2_fused(
    const float* __restrict__ node_emb,
    const float* __restrict__ num_count,
    const int*   __restrict__ seg_ids,
    const int*   __restrict__ last_idx,
    const float* __restrict__ a_g,
    const unsigned short* __restrict__ w2bf,
    const float* __restrict__ q_w,
    const float* __restrict__ q_b,
    float* __restrict__ s_g,
    float* __restrict__ part)
{
    __shared__ __align__(16) char w2s[H_DIM * 256];    // 32 KB, swizzled
    __shared__ float ldsS[MAXLOC][H_DIM];              // 7 KB partial table

    const int tid = threadIdx.x;
    // --- zero partial table + stage W2 bf16 -> LDS, XOR swizzled ---
    {
        float* z = &ldsS[0][0];
        #pragma unroll
        for (int i = tid; i < MAXLOC * H_DIM; i += 512) z[i] = 0.f;
        const uint4* wsrc = reinterpret_cast<const uint4*>(w2bf);
        #pragma unroll
        for (int i = 0; i < 4; i++) {
            int c = i * 512 + tid;
            uint4 v = wsrc[c];
            int byte = c << 4;
            int row  = byte >> 8;
            *reinterpret_cast<uint4*>(w2s + (byte ^ ((row & 7) << 4))) = v;
        }
    }

    // XCD-aware bijective swizzle (3200 % 8 == 0)
    const int bid = (int)blockIdx.x;
    const int swz = (bid & 7) * (NBLK2 / 8) + (bid >> 3);   // logical block id

    const int lane = tid & 63;
    const int wid  = tid >> 6;                 // 0..7
    const int l16 = lane & 15, lq = lane >> 4;
    const int nbB = swz * 128;                 // block's first node row
    const int nb  = nbB + wid * 16;            // this wave's 16 nodes

    const int   sg0 = seg_ids[nbB];            // block's first graph
    const int   sgl = seg_ids[nb + l16];
    const float ncl = num_count[nb + l16];
    const float qb0 = q_b[0];

    // --- a_g row (prescaled) as MFMA C-init ---
    const float* agrow = a_g + (size_t)sgl * H_DIM + lq * 4;
    f32x4 acc[8];
    #pragma unroll
    for (int nt = 0; nt < 8; nt++) {
        float4 a4 = *reinterpret_cast<const float4*>(agrow + nt * 16);
        acc[nt] = f32x4{a4.x, a4.y, a4.z, a4.w};
    }

    // --- node fragments: row l16, cols lq*8 + ks*32 .. +7 (f32 -> bf16) ---
    s16x8 af[4];
    const float* nrow = node_emb + (size_t)(nb + l16) * H_DIM + lq * 8;
    #pragma unroll
    for (int ks = 0; ks < 4; ks++) {
        float4 f0 = *reinterpret_cast<const float4*>(nrow + ks * 32);
        float4 f1 = *reinterpret_cast<const float4*>(nrow + ks * 32 + 4);
        unsigned p0, p1, p2, p3;
        asm("v_cvt_pk_bf16_f32 %0, %1, %2" : "=v"(p0) : "v"(f0.x), "v"(f0.y));
        asm("v_cvt_pk_bf16_f32 %0, %1, %2" : "=v"(p1) : "v"(f0.z), "v"(f0.w));
        asm("v_cvt_pk_bf16_f32 %0, %1, %2" : "=v"(p2) : "v"(f1.x), "v"(f1.y));
        asm("v_cvt_pk_bf16_f32 %0, %1, %2" : "=v"(p3) : "v"(f1.z), "v"(f1.w));
        union { u32x4 u; s16x8 s; } cv;
        cv.u = u32x4{p0, p1, p2, p3};
        af[ks] = cv.s;
    }

    __syncthreads();   // w2s + zeroed ldsS visible

    // --- swapped z-MFMA: lane holds z'[l16][h] = -log2e*(z+a_g) ----------
    #pragma unroll
    for (int ks = 0; ks < 4; ks++) {
        #pragma unroll
        for (int nt = 0; nt < 8; nt++) {
            int row  = nt * 16 + l16;
            int byte = (row << 8) | ((lq * 8 + ks * 32) << 1);
            byte ^= (row & 7) << 4;
            s16x8 wfr = *reinterpret_cast<const s16x8*>(w2s + byte);
            acc[nt] = __builtin_amdgcn_mfma_f32_16x16x32_bf16(wfr, af[ks], acc[nt], 0, 0, 0);
        }
    }

    // --- alpha: sum_h q_w[h] / (1 + exp2(z')); 2-shfl reduce -------------
    float pp0 = 0.f, pp1 = 0.f, pp2 = 0.f, pp3 = 0.f;
    #pragma unroll
    for (int nt = 0; nt < 8; nt++) {
        float4 q4 = *reinterpret_cast<const float4*>(q_w + nt * 16 + lq * 4);
        pp0 += q4.x * __builtin_amdgcn_rcpf(1.f + __builtin_amdgcn_exp2f(acc[nt][0]));
        pp1 += q4.y * __builtin_amdgcn_rcpf(1.f + __builtin_amdgcn_exp2f(acc[nt][1]));
        pp2 += q4.z * __builtin_amdgcn_rcpf(1.f + __builtin_amdgcn_exp2f(acc[nt][2]));
        pp3 += q4.w * __builtin_amdgcn_rcpf(1.f + __builtin_amdgcn_exp2f(acc[nt][3]));
    }
    float p = (pp0 + pp1) + (pp2 + pp3);
    p += __shfl_xor(p, 16, 64);
    p += __shfl_xor(p, 32, 64);
    const float coefl = ncl * (p + qb0);   // coef for node row l16, all lanes

    // --- identity-MFMA transpose: accT[ks][b][rr] = node[lq*4+rr][...] ---
    s16x8 ib[2];
    #pragma unroll
    for (int b = 0; b < 2; b++) {
        int kk = l16 + 16 * b;
        #pragma unroll
        for (int e = 0; e < 8; e++)
            ib[b][e] = (kk == lq * 8 + e) ? (short)0x3F80 : (short)0;
    }
    f32x4 accT[4][2];
    #pragma unroll
    for (int ks = 0; ks < 4; ks++)
        #pragma unroll
        for (int b = 0; b < 2; b++)
            accT[ks][b] = __builtin_amdgcn_mfma_f32_16x16x32_bf16(
                              af[ks], ib[b], f32x4{0.f, 0.f, 0.f, 0.f}, 0, 0, 0);

    // --- segmented sum: shfl-fold then conflict-free ds_add per run ------
    int r0 = 0;
    while (r0 < 16) {
        const int cur = __shfl(sgl, r0, 64);                 // wave-uniform
        unsigned long long diff = __ballot(sgl != cur) & 0xFFFFull;
        diff &= ~((1ull << r0) - 1ull);
        const int r1 = diff ? (int)__builtin_ctzll(diff) : 16;

        const float cmask = (sgl == cur) ? coefl : 0.f;      // masked coef of row l16
        float cm[4];
        #pragma unroll
        for (int rr = 0; rr < 4; rr++)
            cm[rr] = __shfl(cmask, lq * 4 + rr, 64);

        const int loc = cur - sg0;                           // 0..13
        #pragma unroll
        for (int ks = 0; ks < 4; ks++) {
            #pragma unroll
            for (int b = 0; b < 2; b++) {
                float s = cm[0] * accT[ks][b][0] + cm[1] * accT[ks][b][1]
                        + cm[2] * accT[ks][b][2] + cm[3] * accT[ks][b][3];
                s += __shfl_xor(s, 16, 64);
                s += __shfl_xor(s, 32, 64);
                if (lq == 0)
                    atomicAdd(&ldsS[loc][ks * 32 + b * 16 + l16], s);  // ds_add_f32
            }
        }
        r0 = r1;
    }
    __syncthreads();   // partial table complete

    // --- epilogue: interior graphs -> s_g; boundary graphs -> part ------
    {
        const int sgL  = seg_ids[nbB + 127];
        const int nloc = sgL - sg0 + 1;
        const int col  = tid & 127;
        for (int j = tid >> 7; j < nloc; j += 4) {
            const int gg = sg0 + j;
            const int st = gg ? (last_idx[gg - 1] + 1) : 0;
            const int en = last_idx[gg];
            const float v = ldsS[j][col];
            const bool interior = (st >= nbB) && (en < nbB + 128);
            if (interior) {
                s_g[(size_t)gg * H_DIM + col] = v;
            } else if (j == 0) {
                part[((size_t)swz * 2 + 0) * H_DIM + col] = v;   // slot 0
            } else {
                part[((size_t)swz * 2 + 1) * H_DIM + col] = v;   // slot 1 (j==nloc-1)
            }
        }
    }
}

// ---------------- K3: fused boundary gather + [v_n | s_g] @ W3^T + W3_b
__global__ __launch_bounds__(128) void k3_out(
    const float* __restrict__ node_emb,
    const int*   __restrict__ last_idx,
    const float* __restrict__ s_g,
    const float* __restrict__ part,
    const float* __restrict__ W3w,
    const float* __restrict__ W3b,
    float* __restrict__ out)
{
    __shared__ float cat[8][2 * H_DIM];
    const int tid = threadIdx.x;
    const int g0  = blockIdx.x * 8;
    #pragma unroll
    for (int g = 0; g < 8; g++) {
        const int gg = g0 + g;
        const int en = last_idx[gg];
        cat[g][tid] = node_emb[(size_t)en * H_DIM + tid];
        const int st = gg ? (last_idx[gg - 1] + 1) : 0;
        const int bs = st >> 7, be = en >> 7;
        float s;
        if (bs == be) {
            s = s_g[(size_t)gg * H_DIM + tid];         // interior: k2 stored it
        } else {
            const int slot0 = (st == (bs << 7)) ? 0 : 1;
            s = part[((size_t)bs * 2 + slot0) * H_DIM + tid];
            for (int m = bs + 1; m <= be; m++)
                s += part[((size_t)m * 2 + 0) * H_DIM + tid];
        }
        cat[g][H_DIM + tid] = s;
    }
    __syncthreads();
    float acc[8];
    float b = W3b[tid];
    #pragma unroll
    for (int g = 0; g < 8; g++) acc[g] = b;
    const float* wrow = W3w + (size_t)tid * (2 * H_DIM);
    for (int k = 0; k < 2 * H_DIM; k += 4) {
        float4 w = *reinterpret_cast<const float4*>(wrow + k);
        #pragma unroll
        for (int g = 0; g < 8; g++)
            acc[g] += w.x * cat[g][k] + w.y * cat[g][k+1]
                    + w.z * cat[g][k+2] + w.w * cat[g][k+3];
    }
    #pragma unroll
    for (int g = 0; g < 8; g++)
        out[(size_t)(g0 + g) * H_DIM + tid] = acc[g];
}

extern "C" void kernel_launch(void* const* d_in, const int* in_sizes, int n_in,
                              void* d_out, int out_size, void* d_ws, size_t ws_size,
                              hipStream_t stream) {
    const float* node_emb  = (const float*)d_in[0];
    const float* num_count = (const float*)d_in[1];
    // d_in[2] sections: unused
    const int*   seg_ids   = (const int*)d_in[3];
    const int*   last_idx  = (const int*)d_in[4];
    // d_in[5..8] unused
    const float* W1w = (const float*)d_in[9];
    const float* W1b = (const float*)d_in[10];
    const float* W2w = (const float*)d_in[11];
    const float* W2b = (const float*)d_in[12];
    const float* qw  = (const float*)d_in[13];
    const float* qb  = (const float*)d_in[14];
    const float* W3w = (const float*)d_in[15];
    const float* W3b = (const float*)d_in[16];
    float* out = (float*)d_out;

    char* ws = (char*)d_ws;
    float* a_g  = (float*)(ws);                          // 4 MB
    float* s_g  = (float*)(ws + (4u << 20));             // 4 MB
    unsigned short* w2bf = (unsigned short*)(ws + (8u << 20));   // 32 KB
    float* part = (float*)(ws + (9u << 20));             // 3200*2*128*4 = 3.3 MB

    k0_w2   <<<64,         256, 0, stream>>>(W2w, w2bf);
    k1_ag   <<<NGRAPH / 4, 128, 0, stream>>>(node_emb, last_idx, W1w, W1b, W2b, a_g);
    k2_fused<<<NBLK2,      512, 0, stream>>>(node_emb, num_count, seg_ids, last_idx,
                                             a_g, w2bf, qw, qb, s_g, part);
    k3_out  <<<NGRAPH / 8, 128, 0, stream>>>(node_emb, last_idx, s_g, part, W3w, W3b, out);
}

// Round 14
// 96.293 us; speedup vs baseline: 12.4775x; 1.1747x over previous
//
#include <hip/hip_runtime.h>
#include <hip/hip_bf16.h>

// Problem constants (fixed by the reference setup)
#define H_DIM  128
#define NGRAPH 8192
#define NTOTAL 409600
#define NBLK2  (NTOTAL / 128)     // 3200 blocks of 8 waves x 16 nodes

#define NLOG2E -1.4426950408889634f

typedef __attribute__((ext_vector_type(8))) short    s16x8;   // 8 bf16
typedef __attribute__((ext_vector_type(4))) float    f32x4;   // MFMA accumulator
typedef __attribute__((ext_vector_type(4))) unsigned u32x4;

__device__ __forceinline__ unsigned short f2bf(float f) {
    unsigned int u = __float_as_uint(f);
    unsigned int r = u + 0x7fffu + ((u >> 16) & 1u);   // RNE
    return (unsigned short)(r >> 16);
}

// ---------------- K0: prep — W1,W2(prescaled),W3 -> bf16; bsum ---------
__global__ __launch_bounds__(256) void k0_prep(
    const float* __restrict__ W1w, const float* __restrict__ W2w,
    const float* __restrict__ W3w, const float* __restrict__ W1b,
    const float* __restrict__ W2b,
    unsigned short* __restrict__ w1bf, unsigned short* __restrict__ w2bf,
    unsigned short* __restrict__ w3bf, float* __restrict__ bsum)
{
    int i = blockIdx.x * 256 + threadIdx.x;      // 256 blocks -> 65536 ids
    if (i < 16384)      w1bf[i] = f2bf(W1w[i]);
    else if (i < 32768) w2bf[i - 16384] = f2bf(NLOG2E * W2w[i - 16384]);
    else                w3bf[i - 32768] = f2bf(W3w[i - 32768]);
    if (i < H_DIM) bsum[i] = W1b[i] + W2b[i];
}

// ---------------- K1: a_g = -log2e*(v_n @ W1^T + bsum) via MFMA; zero s_g
// 64 blocks x 512 threads (8 waves x 16 graphs). Same swapped-MFMA layout
// as k2 (validated): lane holds z1[g=l16][h=nt*16+lq*4+rr].
__global__ __launch_bounds__(512) void k1_ag(
    const float* __restrict__ node_emb,
    const int*   __restrict__ last_idx,
    const unsigned short* __restrict__ w1bf,
    const float* __restrict__ bsum,
    float* __restrict__ a_g,
    float* __restrict__ s_g)
{
    __shared__ __align__(16) char w1s[H_DIM * 256];   // 32 KB, swizzled

    const int tid = threadIdx.x;
    // --- stage W1 bf16 -> LDS, XOR swizzled (identical pattern to k2) ---
    {
        const uint4* wsrc = reinterpret_cast<const uint4*>(w1bf);
        #pragma unroll
        for (int i = 0; i < 4; i++) {
            int c = i * 512 + tid;
            uint4 v = wsrc[c];
            int byte = c << 4;
            int row  = byte >> 8;
            *reinterpret_cast<uint4*>(w1s + (byte ^ ((row & 7) << 4))) = v;
        }
    }
    // --- zero this block's s_g slice (128 graph rows) ---
    {
        float4* z = reinterpret_cast<float4*>(s_g + (size_t)blockIdx.x * 128 * H_DIM);
        float4 zero = float4{0.f, 0.f, 0.f, 0.f};
        #pragma unroll
        for (int i = 0; i < 8; i++) z[i * 512 + tid] = zero;
    }

    const int lane = tid & 63;
    const int wid  = tid >> 6;
    const int l16 = lane & 15, lq = lane >> 4;
    const int g   = blockIdx.x * 128 + wid * 16 + l16;   // this lane's graph
    const int li  = last_idx[g];

    // --- C-init = bsum[h] ---
    f32x4 acc[8];
    #pragma unroll
    for (int nt = 0; nt < 8; nt++) {
        float4 b4 = *reinterpret_cast<const float4*>(bsum + nt * 16 + lq * 4);
        acc[nt] = f32x4{b4.x, b4.y, b4.z, b4.w};
    }

    // --- v_n fragment: row li, cols lq*8 + ks*32 (f32 -> bf16) ---
    s16x8 vf[4];
    const float* vnrow = node_emb + (size_t)li * H_DIM + lq * 8;
    #pragma unroll
    for (int ks = 0; ks < 4; ks++) {
        float4 f0 = *reinterpret_cast<const float4*>(vnrow + ks * 32);
        float4 f1 = *reinterpret_cast<const float4*>(vnrow + ks * 32 + 4);
        unsigned p0, p1, p2, p3;
        asm("v_cvt_pk_bf16_f32 %0, %1, %2" : "=v"(p0) : "v"(f0.x), "v"(f0.y));
        asm("v_cvt_pk_bf16_f32 %0, %1, %2" : "=v"(p1) : "v"(f0.z), "v"(f0.w));
        asm("v_cvt_pk_bf16_f32 %0, %1, %2" : "=v"(p2) : "v"(f1.x), "v"(f1.y));
        asm("v_cvt_pk_bf16_f32 %0, %1, %2" : "=v"(p3) : "v"(f1.z), "v"(f1.w));
        union { u32x4 u; s16x8 s; } cv;
        cv.u = u32x4{p0, p1, p2, p3};
        vf[ks] = cv.s;
    }

    __syncthreads();   // w1s ready

    // --- swapped z-MFMA: acc[nt] += W1(rows nt*16+..) x v_n ---
    #pragma unroll
    for (int ks = 0; ks < 4; ks++) {
        #pragma unroll
        for (int nt = 0; nt < 8; nt++) {
            int row  = nt * 16 + l16;
            int byte = (row << 8) | ((lq * 8 + ks * 32) << 1);
            byte ^= (row & 7) << 4;
            s16x8 wfr = *reinterpret_cast<const s16x8*>(w1s + byte);
            acc[nt] = __builtin_amdgcn_mfma_f32_16x16x32_bf16(wfr, vf[ks], acc[nt], 0, 0, 0);
        }
    }

    // --- store a_g row (prescaled by -log2e) ---
    float* arow = a_g + (size_t)g * H_DIM + lq * 4;
    #pragma unroll
    for (int nt = 0; nt < 8; nt++) {
        float4 o;
        o.x = NLOG2E * acc[nt][0];
        o.y = NLOG2E * acc[nt][1];
        o.z = NLOG2E * acc[nt][2];
        o.w = NLOG2E * acc[nt][3];
        *reinterpret_cast<float4*>(arow + nt * 16) = o;
    }
}

// ---------------- K2: one-shot fused alpha + segment-sum (R10 verbatim)
__global__ __launch_bounds__(512, 6) void k2_fused(
    const float* __restrict__ node_emb,
    const float* __restrict__ num_count,
    const int*   __restrict__ seg_ids,
    const float* __restrict__ a_g,
    const unsigned short* __restrict__ w2bf,
    const float* __restrict__ q_w,
    const float* __restrict__ q_b,
    float* __restrict__ s_g)
{
    __shared__ __align__(16) char w2s[H_DIM * 256];   // 32 KB, swizzled

    const int tid = threadIdx.x;
    {
        const uint4* wsrc = reinterpret_cast<const uint4*>(w2bf);
        #pragma unroll
        for (int i = 0; i < 4; i++) {
            int c = i * 512 + tid;
            uint4 v = wsrc[c];
            int byte = c << 4;
            int row  = byte >> 8;
            *reinterpret_cast<uint4*>(w2s + (byte ^ ((row & 7) << 4))) = v;
        }
    }

    const int bid = (int)blockIdx.x;
    const int swz = (bid & 7) * (NBLK2 / 8) + (bid >> 3);

    const int lane = tid & 63;
    const int wid  = tid >> 6;
    const int l16 = lane & 15, lq = lane >> 4;
    const int nb  = (swz * 8 + wid) * 16;

    const int   sgl = seg_ids[nb + l16];
    const float ncl = num_count[nb + l16];
    const float qb0 = q_b[0];

    const float* agrow = a_g + (size_t)sgl * H_DIM + lq * 4;
    f32x4 acc[8];
    #pragma unroll
    for (int nt = 0; nt < 8; nt++) {
        float4 a4 = *reinterpret_cast<const float4*>(agrow + nt * 16);
        acc[nt] = f32x4{a4.x, a4.y, a4.z, a4.w};
    }

    s16x8 af[4];
    const float* nrow = node_emb + (size_t)(nb + l16) * H_DIM + lq * 8;
    #pragma unroll
    for (int ks = 0; ks < 4; ks++) {
        float4 f0 = *reinterpret_cast<const float4*>(nrow + ks * 32);
        float4 f1 = *reinterpret_cast<const float4*>(nrow + ks * 32 + 4);
        unsigned p0, p1, p2, p3;
        asm("v_cvt_pk_bf16_f32 %0, %1, %2" : "=v"(p0) : "v"(f0.x), "v"(f0.y));
        asm("v_cvt_pk_bf16_f32 %0, %1, %2" : "=v"(p1) : "v"(f0.z), "v"(f0.w));
        asm("v_cvt_pk_bf16_f32 %0, %1, %2" : "=v"(p2) : "v"(f1.x), "v"(f1.y));
        asm("v_cvt_pk_bf16_f32 %0, %1, %2" : "=v"(p3) : "v"(f1.z), "v"(f1.w));
        union { u32x4 u; s16x8 s; } cv;
        cv.u = u32x4{p0, p1, p2, p3};
        af[ks] = cv.s;
    }

    __syncthreads();   // w2s ready (only barrier)

    #pragma unroll
    for (int ks = 0; ks < 4; ks++) {
        #pragma unroll
        for (int nt = 0; nt < 8; nt++) {
            int row  = nt * 16 + l16;
            int byte = (row << 8) | ((lq * 8 + ks * 32) << 1);
            byte ^= (row & 7) << 4;
            s16x8 wfr = *reinterpret_cast<const s16x8*>(w2s + byte);
            acc[nt] = __builtin_amdgcn_mfma_f32_16x16x32_bf16(wfr, af[ks], acc[nt], 0, 0, 0);
        }
    }

    float pp0 = 0.f, pp1 = 0.f, pp2 = 0.f, pp3 = 0.f;
    #pragma unroll
    for (int nt = 0; nt < 8; nt++) {
        float4 q4 = *reinterpret_cast<const float4*>(q_w + nt * 16 + lq * 4);
        pp0 += q4.x * __builtin_amdgcn_rcpf(1.f + __builtin_amdgcn_exp2f(acc[nt][0]));
        pp1 += q4.y * __builtin_amdgcn_rcpf(1.f + __builtin_amdgcn_exp2f(acc[nt][1]));
        pp2 += q4.z * __builtin_amdgcn_rcpf(1.f + __builtin_amdgcn_exp2f(acc[nt][2]));
        pp3 += q4.w * __builtin_amdgcn_rcpf(1.f + __builtin_amdgcn_exp2f(acc[nt][3]));
    }
    float p = (pp0 + pp1) + (pp2 + pp3);
    p += __shfl_xor(p, 16, 64);
    p += __shfl_xor(p, 32, 64);
    const float coefl = ncl * (p + qb0);   // coef for node row l16, all lanes

    s16x8 ib[2];
    #pragma unroll
    for (int b = 0; b < 2; b++) {
        int kk = l16 + 16 * b;
        #pragma unroll
        for (int e = 0; e < 8; e++)
            ib[b][e] = (kk == lq * 8 + e) ? (short)0x3F80 : (short)0;
    }
    f32x4 accT[4][2];
    #pragma unroll
    for (int ks = 0; ks < 4; ks++)
        #pragma unroll
        for (int b = 0; b < 2; b++)
            accT[ks][b] = __builtin_amdgcn_mfma_f32_16x16x32_bf16(
                              af[ks], ib[b], f32x4{0.f, 0.f, 0.f, 0.f}, 0, 0, 0);

    int r0 = 0;
    while (r0 < 16) {
        const int cur = __shfl(sgl, r0, 64);                 // wave-uniform
        unsigned long long diff = __ballot(sgl != cur) & 0xFFFFull;
        diff &= ~((1ull << r0) - 1ull);
        const int r1 = diff ? (int)__builtin_ctzll(diff) : 16;

        const float cmask = (sgl == cur) ? coefl : 0.f;      // masked coef of row l16
        float cm[4];
        #pragma unroll
        for (int rr = 0; rr < 4; rr++)
            cm[rr] = __shfl(cmask, lq * 4 + rr, 64);

        #pragma unroll
        for (int ks = 0; ks < 4; ks++) {
            #pragma unroll
            for (int b = 0; b < 2; b++) {
                float s = cm[0] * accT[ks][b][0] + cm[1] * accT[ks][b][1]
                        + cm[2] * accT[ks][b][2] + cm[3] * accT[ks][b][3];
                s += __shfl_xor(s, 16, 64);
                s += __shfl_xor(s, 32, 64);
                if (lq == 0)
                    atomicAdd(s_g + (size_t)cur * H_DIM + ks * 32 + b * 16 + l16, s);
            }
        }
        r0 = r1;
    }
}

// ---------------- K3: s_h = [v_n | s_g] @ W3^T + W3_b  (W3 in bf16) ----
__global__ __launch_bounds__(128) void k3_out(
    const float* __restrict__ node_emb,
    const int*   __restrict__ last_idx,
    const float* __restrict__ s_g,
    const unsigned short* __restrict__ w3bf,
    const float* __restrict__ W3b,
    float* __restrict__ out)
{
    __shared__ float cat[8][2 * H_DIM];
    const int tid = threadIdx.x;
    const int g0  = blockIdx.x * 8;
    #pragma unroll
    for (int g = 0; g < 8; g++) {
        cat[g][tid]         = node_emb[(size_t)last_idx[g0 + g] * H_DIM + tid];
        cat[g][H_DIM + tid] = s_g[(size_t)(g0 + g) * H_DIM + tid];
    }
    __syncthreads();
    float acc[8];
    float b = W3b[tid];
    #pragma unroll
    for (int g = 0; g < 8; g++) acc[g] = b;
    const uint2* wrow = reinterpret_cast<const uint2*>(w3bf + (size_t)tid * (2 * H_DIM));
    for (int k = 0; k < 2 * H_DIM; k += 4) {
        uint2 w = wrow[k >> 2];
        float w0 = __uint_as_float(w.x << 16);
        float w1 = __uint_as_float(w.x & 0xffff0000u);
        float w2 = __uint_as_float(w.y << 16);
        float w3 = __uint_as_float(w.y & 0xffff0000u);
        #pragma unroll
        for (int g = 0; g < 8; g++)
            acc[g] += w0 * cat[g][k] + w1 * cat[g][k+1]
                    + w2 * cat[g][k+2] + w3 * cat[g][k+3];
    }
    #pragma unroll
    for (int g = 0; g < 8; g++)
        out[(size_t)(g0 + g) * H_DIM + tid] = acc[g];
}

extern "C" void kernel_launch(void* const* d_in, const int* in_sizes, int n_in,
                              void* d_out, int out_size, void* d_ws, size_t ws_size,
                              hipStream_t stream) {
    const float* node_emb  = (const float*)d_in[0];
    const float* num_count = (const float*)d_in[1];
    // d_in[2] sections: unused
    const int*   seg_ids   = (const int*)d_in[3];
    const int*   last_idx  = (const int*)d_in[4];
    // d_in[5..8] unused
    const float* W1w = (const float*)d_in[9];
    const float* W1b = (const float*)d_in[10];
    const float* W2w = (const float*)d_in[11];
    const float* W2b = (const float*)d_in[12];
    const float* qw  = (const float*)d_in[13];
    const float* qb  = (const float*)d_in[14];
    const float* W3w = (const float*)d_in[15];
    const float* W3b = (const float*)d_in[16];
    float* out = (float*)d_out;

    char* ws = (char*)d_ws;
    float* a_g = (float*)(ws);                                   // 4 MB
    float* s_g = (float*)(ws + (4u << 20));                      // 4 MB
    unsigned short* w2bf = (unsigned short*)(ws + (8u << 20));          // 32 KB
    unsigned short* w1bf = (unsigned short*)(ws + (8u << 20) + 32768);  // 32 KB
    unsigned short* w3bf = (unsigned short*)(ws + (8u << 20) + 65536);  // 64 KB
    float* bsum          = (float*)(ws + (8u << 20) + 131072);          // 512 B

    k0_prep<<<256,        256, 0, stream>>>(W1w, W2w, W3w, W1b, W2b,
                                            w1bf, w2bf, w3bf, bsum);
    k1_ag  <<<NGRAPH/128, 512, 0, stream>>>(node_emb, last_idx, w1bf, bsum, a_g, s_g);
    k2_fused<<<NBLK2,     512, 0, stream>>>(node_emb, num_count, seg_ids, a_g,
                                            w2bf, qw, qb, s_g);
    k3_out <<<NGRAPH/8,   128, 0, stream>>>(node_emb, last_idx, s_g, w3bf, W3b, out);
}